// Round 3
// baseline (324.044 us; speedup 1.0000x reference)
//
#include <hip/hip_runtime.h>
#include <math.h>

#define NUM_EMB 512
#define EDIM 64
#define BATCH 32
#define HW 4096
#define NROWS (BATCH * HW)        // 131072
#define NQ (NROWS * EDIM)         // 8388608

// numpy pairwise_sum for n=64 contiguous fp32: 8 stride-8 accumulators,
// tree combine ((r0+r1)+(r2+r3)) + ((r4+r5)+(r6+r7)). No FMA contraction.
__device__ __forceinline__ float pairwise8_64(const float* v) {
    float r0 = v[0], r1 = v[1], r2 = v[2], r3 = v[3];
    float r4 = v[4], r5 = v[5], r6 = v[6], r7 = v[7];
#pragma unroll
    for (int i = 8; i < 64; i += 8) {
        r0 = __fadd_rn(r0, v[i + 0]);
        r1 = __fadd_rn(r1, v[i + 1]);
        r2 = __fadd_rn(r2, v[i + 2]);
        r3 = __fadd_rn(r3, v[i + 3]);
        r4 = __fadd_rn(r4, v[i + 4]);
        r5 = __fadd_rn(r5, v[i + 5]);
        r6 = __fadd_rn(r6, v[i + 6]);
        r7 = __fadd_rn(r7, v[i + 7]);
    }
    return __fadd_rn(__fadd_rn(__fadd_rn(r0, r1), __fadd_rn(r2, r3)),
                     __fadd_rn(__fadd_rn(r4, r5), __fadd_rn(r6, r7)));
}

// ws_f layout: [0] = loss sum accumulator, [8..8+511] = t2[k] = ||emb_k||^2
__global__ void vq_prep(const float* __restrict__ emb, float* __restrict__ ws_f) {
    int k = blockIdx.x * blockDim.x + threadIdx.x;
    if (k == 0) ws_f[0] = 0.0f;
    if (k < NUM_EMB) {
        const float* e = emb + k * EDIM;
        float sq[EDIM];
#pragma unroll
        for (int c = 0; c < EDIM; ++c) sq[c] = __fmul_rn(e[c], e[c]);
        ws_f[8 + k] = pairwise8_64(sq);
    }
}

__global__ __launch_bounds__(256, 2) void vq_main(const float* __restrict__ z,
                                                  const float* __restrict__ emb,
                                                  float* __restrict__ out,
                                                  float* __restrict__ ws_f) {
    const int r = blockIdx.x * 256 + threadIdx.x;  // row in [0, NROWS)
    const int b = r >> 12;                         // batch
    const int hw = r & 4095;                       // h*64+w

    // x[c] = z[b, c, hw]  (coalesced across threads for each c)
    const float* zb = z + (size_t)b * (EDIM * HW) + hw;
    float x[EDIM];
#pragma unroll
    for (int c = 0; c < EDIM; ++c) x[c] = zb[(size_t)c * HW];

    // Pin every x[c] into a VGPR: the empty asm makes each value opaque, so
    // the register allocator cannot "rematerialize" it by re-loading z inside
    // the 512-iteration k-loop (the round-1/2 failure mode: VGPR=48, 2.5x
    // VALU bloat from reload address math, 57% vmcnt stall).
#pragma unroll
    for (int c = 0; c < EDIM; ++c) asm volatile("" : "+v"(x[c]));

    // t1 = ||x||^2, numpy pairwise order
    float sq[EDIM];
#pragma unroll
    for (int c = 0; c < EDIM; ++c) sq[c] = __fmul_rn(x[c], x[c]);
    const float t1 = pairwise8_64(sq);

    const float* __restrict__ t2 = ws_f + 8;

    float best = INFINITY;
    int bestk = 0;

    for (int k = 0; k < NUM_EMB; k += 4) {
        // wave-uniform addresses -> scalar s_loads into SGPRs (free for VALU)
        const float* e0 = emb + (size_t)(k + 0) * EDIM;
        const float* e1 = emb + (size_t)(k + 1) * EDIM;
        const float* e2 = emb + (size_t)(k + 2) * EDIM;
        const float* e3 = emb + (size_t)(k + 3) * EDIM;
        float a0 = 0.0f, a1 = 0.0f, a2 = 0.0f, a3 = 0.0f;
#pragma unroll
        for (int c = 0; c < EDIM; ++c) {
            a0 = __fmaf_rn(x[c], e0[c], a0);
            a1 = __fmaf_rn(x[c], e1[c], a1);
            a2 = __fmaf_rn(x[c], e2[c], a2);
            a3 = __fmaf_rn(x[c], e3[c], a3);
        }
        // d = fl(fl(t1 + t2) - fl(2*p)); strict < keeps lowest index on ties
        float d0 = __fsub_rn(__fadd_rn(t1, t2[k + 0]), __fmul_rn(2.0f, a0));
        float d1 = __fsub_rn(__fadd_rn(t1, t2[k + 1]), __fmul_rn(2.0f, a1));
        float d2 = __fsub_rn(__fadd_rn(t1, t2[k + 2]), __fmul_rn(2.0f, a2));
        float d3 = __fsub_rn(__fadd_rn(t1, t2[k + 3]), __fmul_rn(2.0f, a3));
        if (d0 < best) { best = d0; bestk = k + 0; }
        if (d1 < best) { best = d1; bestk = k + 1; }
        if (d2 < best) { best = d2; bestk = k + 2; }
        if (d3 < best) { best = d3; bestk = k + 3; }
    }

    // Epilogue: write qst (forward == fl(x + fl(q - x))), accumulate loss, idx.
    const float* eb = emb + (size_t)bestk * EDIM;
    float s = 0.0f;
#pragma unroll
    for (int c = 0; c < EDIM; ++c) {
        float q = eb[c];                      // divergent gather, L2-resident table
        float diff = __fsub_rn(q, x[c]);      // q - z
        out[(size_t)(b * EDIM + c) * HW + hw] = __fadd_rn(x[c], diff);
        s = __fmaf_rn(diff, diff, s);
    }

    out[(size_t)NQ + 2 + r] = (float)bestk;   // idx as fp32

    // wave-level reduction of loss partial, one atomic per wave
#pragma unroll
    for (int off = 32; off > 0; off >>= 1) s += __shfl_down(s, off);
    if ((threadIdx.x & 63) == 0) atomicAdd(ws_f, s);
}

__global__ void vq_final(const float* __restrict__ ws_f, float* __restrict__ out) {
    float m = ws_f[0] * (1.0f / (float)NQ);   // 2^-23, exact scaling
    out[NQ + 0] = m;
    out[NQ + 1] = m;
}

extern "C" void kernel_launch(void* const* d_in, const int* in_sizes, int n_in,
                              void* d_out, int out_size, void* d_ws, size_t ws_size,
                              hipStream_t stream) {
    const float* z = (const float*)d_in[0];     // [32, 64, 64, 64] fp32
    const float* emb = (const float*)d_in[1];   // [512, 64] fp32
    float* out = (float*)d_out;
    float* ws_f = (float*)d_ws;

    hipLaunchKernelGGL(vq_prep, dim3(1), dim3(512), 0, stream, emb, ws_f);
    hipLaunchKernelGGL(vq_main, dim3(NROWS / 256), dim3(256), 0, stream, z, emb, out, ws_f);
    hipLaunchKernelGGL(vq_final, dim3(1), dim3(1), 0, stream, ws_f, out);
}

// Round 4
// 323.801 us; speedup vs baseline: 1.0008x; 1.0008x over previous
//
#include <hip/hip_runtime.h>
#include <math.h>

#define NUM_EMB 512
#define EDIM 64
#define BATCH 32
#define HW 4096
#define NROWS (BATCH * HW)        // 131072
#define NQ (NROWS * EDIM)         // 8388608

// Apply F at every literal channel index 0..63 (literal tokens so x##c works).
#define DO64(F) \
  F(0) F(1) F(2) F(3) F(4) F(5) F(6) F(7) \
  F(8) F(9) F(10) F(11) F(12) F(13) F(14) F(15) \
  F(16) F(17) F(18) F(19) F(20) F(21) F(22) F(23) \
  F(24) F(25) F(26) F(27) F(28) F(29) F(30) F(31) \
  F(32) F(33) F(34) F(35) F(36) F(37) F(38) F(39) \
  F(40) F(41) F(42) F(43) F(44) F(45) F(46) F(47) \
  F(48) F(49) F(50) F(51) F(52) F(53) F(54) F(55) \
  F(56) F(57) F(58) F(59) F(60) F(61) F(62) F(63)

// numpy pairwise_sum for n=64 contiguous fp32 (used only in tiny prep kernel).
__device__ __forceinline__ float pairwise8_64(const float* v) {
    float r0 = v[0], r1 = v[1], r2 = v[2], r3 = v[3];
    float r4 = v[4], r5 = v[5], r6 = v[6], r7 = v[7];
#pragma unroll
    for (int i = 8; i < 64; i += 8) {
        r0 = __fadd_rn(r0, v[i + 0]);
        r1 = __fadd_rn(r1, v[i + 1]);
        r2 = __fadd_rn(r2, v[i + 2]);
        r3 = __fadd_rn(r3, v[i + 3]);
        r4 = __fadd_rn(r4, v[i + 4]);
        r5 = __fadd_rn(r5, v[i + 5]);
        r6 = __fadd_rn(r6, v[i + 6]);
        r7 = __fadd_rn(r7, v[i + 7]);
    }
    return __fadd_rn(__fadd_rn(__fadd_rn(r0, r1), __fadd_rn(r2, r3)),
                     __fadd_rn(__fadd_rn(r4, r5), __fadd_rn(r6, r7)));
}

// ws_f layout: [0] = loss sum accumulator, [8..8+511] = t2[k] = ||emb_k||^2
__global__ void vq_prep(const float* __restrict__ emb, float* __restrict__ ws_f) {
    int k = blockIdx.x * blockDim.x + threadIdx.x;
    if (k == 0) ws_f[0] = 0.0f;
    if (k < NUM_EMB) {
        const float* e = emb + k * EDIM;
        float sq[EDIM];
#pragma unroll
        for (int c = 0; c < EDIM; ++c) sq[c] = __fmul_rn(e[c], e[c]);
        ws_f[8 + k] = pairwise8_64(sq);
    }
}

#define SEQ8(a, b, c, d, e, f, g, h) \
    __fadd_rn(__fadd_rn(__fadd_rn(__fadd_rn(__fadd_rn(__fadd_rn(__fadd_rn(a, b), c), d), e), f), g), h)

__global__ __launch_bounds__(256, 2) void vq_main(const float* __restrict__ z,
                                                  const float* __restrict__ emb,
                                                  float* __restrict__ out,
                                                  float* __restrict__ ws_f) {
    const int r = blockIdx.x * 256 + threadIdx.x;  // row in [0, NROWS)
    const int b = r >> 12;                         // batch
    const int hw = r & 4095;                       // h*64+w

    // x as 64 NAMED scalars — no array, no pointer escape, no scratch.
    const float* zb = z + (size_t)b * (EDIM * HW) + hw;
#define LOADX(c) float x##c = zb[(size_t)(c) * HW];
    DO64(LOADX)
#undef LOADX

    // t1 = ||x||^2 in exact numpy pairwise-8 order (named scalars).
#define SQX(c) float sq##c = __fmul_rn(x##c, x##c);
    DO64(SQX)
#undef SQX
    float r0 = SEQ8(sq0, sq8, sq16, sq24, sq32, sq40, sq48, sq56);
    float r1 = SEQ8(sq1, sq9, sq17, sq25, sq33, sq41, sq49, sq57);
    float r2 = SEQ8(sq2, sq10, sq18, sq26, sq34, sq42, sq50, sq58);
    float r3 = SEQ8(sq3, sq11, sq19, sq27, sq35, sq43, sq51, sq59);
    float r4 = SEQ8(sq4, sq12, sq20, sq28, sq36, sq44, sq52, sq60);
    float r5 = SEQ8(sq5, sq13, sq21, sq29, sq37, sq45, sq53, sq61);
    float r6 = SEQ8(sq6, sq14, sq22, sq30, sq38, sq46, sq54, sq62);
    float r7 = SEQ8(sq7, sq15, sq23, sq31, sq39, sq47, sq55, sq63);
    const float t1 = __fadd_rn(__fadd_rn(__fadd_rn(r0, r1), __fadd_rn(r2, r3)),
                               __fadd_rn(__fadd_rn(r4, r5), __fadd_rn(r6, r7)));

    const float* __restrict__ t2 = ws_f + 8;

    float best = INFINITY;
    int bestk = 0;

    for (int k = 0; k < NUM_EMB; k += 4) {
        // wave-uniform addresses -> scalar s_loads into SGPRs
        const float* e0 = emb + (size_t)(k + 0) * EDIM;
        const float* e1 = emb + (size_t)(k + 1) * EDIM;
        const float* e2 = emb + (size_t)(k + 2) * EDIM;
        const float* e3 = emb + (size_t)(k + 3) * EDIM;
        float a0 = 0.0f, a1 = 0.0f, a2 = 0.0f, a3 = 0.0f;
        // Sequential c-order FMA chain per k — bit-identical to prior rounds.
#define FMA4(c) \
        a0 = __fmaf_rn(x##c, e0[c], a0); \
        a1 = __fmaf_rn(x##c, e1[c], a1); \
        a2 = __fmaf_rn(x##c, e2[c], a2); \
        a3 = __fmaf_rn(x##c, e3[c], a3);
        DO64(FMA4)
#undef FMA4
        // d = fl(fl(t1 + t2) - fl(2*p)); strict < keeps lowest index on ties
        float d0 = __fsub_rn(__fadd_rn(t1, t2[k + 0]), __fmul_rn(2.0f, a0));
        float d1 = __fsub_rn(__fadd_rn(t1, t2[k + 1]), __fmul_rn(2.0f, a1));
        float d2 = __fsub_rn(__fadd_rn(t1, t2[k + 2]), __fmul_rn(2.0f, a2));
        float d3 = __fsub_rn(__fadd_rn(t1, t2[k + 3]), __fmul_rn(2.0f, a3));
        if (d0 < best) { best = d0; bestk = k + 0; }
        if (d1 < best) { best = d1; bestk = k + 1; }
        if (d2 < best) { best = d2; bestk = k + 2; }
        if (d3 < best) { best = d3; bestk = k + 3; }
    }

    // Epilogue: qst forward == fl(x + fl(q - x)); loss partial; idx.
    const float* eb = emb + (size_t)bestk * EDIM;
    float s = 0.0f;
#define EPI(c) { \
        float q = eb[c]; \
        float diff = __fsub_rn(q, x##c); \
        out[(size_t)(b * EDIM + (c)) * HW + hw] = __fadd_rn(x##c, diff); \
        s = __fmaf_rn(diff, diff, s); }
    DO64(EPI)
#undef EPI

    out[(size_t)NQ + 2 + r] = (float)bestk;   // idx as fp32

    // wave-level reduction of loss partial, one atomic per wave
#pragma unroll
    for (int off = 32; off > 0; off >>= 1) s += __shfl_down(s, off);
    if ((threadIdx.x & 63) == 0) atomicAdd(ws_f, s);
}

__global__ void vq_final(const float* __restrict__ ws_f, float* __restrict__ out) {
    float m = ws_f[0] * (1.0f / (float)NQ);   // 2^-23, exact scaling
    out[NQ + 0] = m;
    out[NQ + 1] = m;
}

extern "C" void kernel_launch(void* const* d_in, const int* in_sizes, int n_in,
                              void* d_out, int out_size, void* d_ws, size_t ws_size,
                              hipStream_t stream) {
    const float* z = (const float*)d_in[0];     // [32, 64, 64, 64] fp32
    const float* emb = (const float*)d_in[1];   // [512, 64] fp32
    float* out = (float*)d_out;
    float* ws_f = (float*)d_ws;

    hipLaunchKernelGGL(vq_prep, dim3(1), dim3(512), 0, stream, emb, ws_f);
    hipLaunchKernelGGL(vq_main, dim3(NROWS / 256), dim3(256), 0, stream, z, emb, out, ws_f);
    hipLaunchKernelGGL(vq_final, dim3(1), dim3(1), 0, stream, ws_f, out);
}